// Round 4
// baseline (250.591 us; speedup 1.0000x reference)
//
#include <hip/hip_runtime.h>
#include <hip/hip_bf16.h>

// ALiBi attention, B=8 L=1024 H=8 E=64, fp32 in/out, bf16 MFMA inside.
// Outputs: V [B,L,H,E] then series [B,H,L,L] concatenated in d_out.
// Two-pass fixed-max softmax. Pass A: barrier-free, K loaded global->frag
// (L2-resident via XCD-aware block map). Pass B: K direct again, V LDS
// double-buffered with register prefetch (1 barrier/chunk), wave-private P.

typedef short short8 __attribute__((ext_vector_type(8)));
typedef float f32x4 __attribute__((ext_vector_type(4)));
typedef unsigned short u16x4 __attribute__((ext_vector_type(4)));

#define B_ 8
#define L_ 1024
#define H_ 8
#define E_ 64
#define RSTRIDE (H_ * E_)  // 512 floats between consecutive seq rows
#define QBLK 64            // 4 waves x 16 q-rows
#define CHUNK 64           // keys per pass-B chunk
#define NCH (L_ / CHUNK)

__device__ __forceinline__ unsigned short f2bf(float f) {
  return __builtin_bit_cast(unsigned short, __float2bfloat16(f));
}
__device__ __forceinline__ float bf2f(unsigned short u) {
  return __builtin_bit_cast(float, (unsigned int)u << 16);
}
// load 8 consecutive fp32, convert to bf16x8 fragment
__device__ __forceinline__ short8 ldfrag(const float* p) {
  float4 a = *reinterpret_cast<const float4*>(p);
  float4 b = *reinterpret_cast<const float4*>(p + 4);
  return (short8){(short)f2bf(a.x), (short)f2bf(a.y), (short)f2bf(a.z),
                  (short)f2bf(a.w), (short)f2bf(b.x), (short)f2bf(b.y),
                  (short)f2bf(b.z), (short)f2bf(b.w)};
}

__device__ __forceinline__ void loadV(const float* vchunk, int lane, int w,
                                      float (&R)[16]) {
  const float* vp = vchunk + (size_t)(4 * w) * RSTRIDE + lane;
#pragma unroll
  for (int i = 0; i < 4; ++i)
#pragma unroll
    for (int j = 0; j < 4; ++j) R[4 * i + j] = vp[(size_t)(16 * i + j) * RSTRIDE];
}

__device__ __forceinline__ void storeV(unsigned short* buf, int lane, int w,
                                       const float (&R)[16]) {
#pragma unroll
  for (int i = 0; i < 4; ++i) {
    const int s4 = 4 * w + 16 * i;
    u16x4 u = {f2bf(R[4 * i]), f2bf(R[4 * i + 1]), f2bf(R[4 * i + 2]),
               f2bf(R[4 * i + 3])};
    *reinterpret_cast<u16x4*>(
        &buf[lane * 64 + (((s4 >> 3) ^ (lane & 7)) << 3) + (s4 & 7)]) = u;
  }
}

__device__ __forceinline__ void computeChunk(
    int c, const unsigned short* vbuf, unsigned short* sPw, const float* Kb,
    float* Pb, short8 qf0, short8 qf1, int col, int kg, int lane,
    float sc_l2e, float sl_l2e, const float (&minv)[4], f32x4 (&oacc)[4]) {
  // QK^T (K direct from global/L2), P -> wave-private LDS
#pragma unroll
  for (int kt = 0; kt < 4; ++kt) {
    const int key = c * CHUNK + 16 * kt + col;
    const float* kp = Kb + (size_t)key * RSTRIDE + 8 * kg;
    f32x4 acc = {0.f, 0.f, 0.f, 0.f};
    acc = __builtin_amdgcn_mfma_f32_16x16x32_bf16(qf0, ldfrag(kp), acc, 0, 0, 0);
    acc = __builtin_amdgcn_mfma_f32_16x16x32_bf16(qf1, ldfrag(kp + 32), acc, 0, 0, 0);
    const float vb = sl_l2e * (float)(key - (L_ - 1)) - 32.0f;
#pragma unroll
    for (int r = 0; r < 4; ++r) {
      const float pf = exp2f(acc[r] * sc_l2e + vb) * minv[r];
      const int row = 4 * kg + r;
      sPw[row * 64 + ((((16 * kt + col) >> 3) ^ (row & 7)) << 3) + (col & 7)] =
          f2bf(pf);
    }
  }
  // PV: O += P * V
#pragma unroll
  for (int ks = 0; ks < 2; ++ks) {
    short8 af = *reinterpret_cast<const short8*>(
        &sPw[col * 64 + (((4 * ks + kg) ^ (col & 7)) << 3)]);
#pragma unroll
    for (int et = 0; et < 4; ++et) {
      const int er = 16 * et + col;
      short8 vf = *reinterpret_cast<const short8*>(
          &vbuf[er * 64 + (((4 * ks + kg) ^ (er & 7)) << 3)]);
      oacc[et] =
          __builtin_amdgcn_mfma_f32_16x16x32_bf16(af, vf, oacc[et], 0, 0, 0);
    }
  }
  // coalesced P writeback (wave-private LDS -> fp32 rows)
#pragma unroll
  for (int i = 0; i < 4; ++i) {
    const int f = i * 64 + lane;
    const int row = f >> 4;
    const int c0 = 4 * (f & 15);
    u16x4 u = *reinterpret_cast<const u16x4*>(
        &sPw[row * 64 + (((c0 >> 3) ^ (row & 7)) << 3) + (c0 & 7)]);
    f32x4 o = {bf2f(u[0]), bf2f(u[1]), bf2f(u[2]), bf2f(u[3])};
    __builtin_nontemporal_store(
        o, reinterpret_cast<f32x4*>(&Pb[(size_t)row * L_ + c * CHUNK + c0]));
  }
}

__global__ __launch_bounds__(256, 4) void alibi_attn(
    const float* __restrict__ Qg, const float* __restrict__ Kg,
    const float* __restrict__ Vg, float* __restrict__ Vout,
    float* __restrict__ Pout) {
  __shared__ unsigned short sVT[2][E_ * 64];  // double-buffered V^T, swizzled
  __shared__ unsigned short sP[4][16 * 64];   // per-wave P tile, swizzled

  const int t = threadIdx.x;
  const int lane = t & 63;
  const int w = t >> 6;
  const int col = lane & 15;
  const int kg = lane >> 4;

  // XCD-aware decode: same-(b,h) blocks share id%64 -> same XCD -> K/V L2-hot
  const int id = blockIdx.x;
  const int qb = id >> 6;
  const int bh = id & 63;
  const int h = bh & 7;
  const int b = bh >> 3;
  const int q0 = qb * QBLK;

  const float sc_l2e = 0.125f * 1.44269504f;
  const float sl_l2e = exp2f(-(float)(h + 1) * 0.125f) * 1.44269504f;

  const float* Kb = Kg + ((size_t)b * L_) * RSTRIDE + h * E_;
  const float* Vb = Vg + ((size_t)b * L_) * RSTRIDE + h * E_;

  // ---- Q fragments: row=lane&15, k=8*kg+j (+32 for second frag) ----
  short8 qf0, qf1;
  {
    const float* qp =
        Qg + ((size_t)b * L_ + q0 + 16 * w + col) * RSTRIDE + h * E_ + 8 * kg;
    qf0 = ldfrag(qp);
    qf1 = ldfrag(qp + 32);
  }

  // ======== Pass A: z = sum exp2(u-32); no LDS, no barriers ========
  float z_[4] = {0.f, 0.f, 0.f, 0.f};
#pragma unroll 4
  for (int kt = 0; kt < L_ / 16; ++kt) {
    const int key = 16 * kt + col;
    const float* kp = Kb + (size_t)key * RSTRIDE + 8 * kg;
    f32x4 acc = {0.f, 0.f, 0.f, 0.f};
    acc = __builtin_amdgcn_mfma_f32_16x16x32_bf16(qf0, ldfrag(kp), acc, 0, 0, 0);
    acc = __builtin_amdgcn_mfma_f32_16x16x32_bf16(qf1, ldfrag(kp + 32), acc, 0, 0, 0);
    const float vb = sl_l2e * (float)(key - (L_ - 1)) - 32.0f;
#pragma unroll
    for (int r = 0; r < 4; ++r) z_[r] += exp2f(acc[r] * sc_l2e + vb);
  }

  // combine z across the 16 lanes sharing each row
  float minv[4];
#pragma unroll
  for (int r = 0; r < 4; ++r) {
    float z = z_[r];
#pragma unroll
    for (int off = 1; off < 16; off <<= 1) z += __shfl_xor(z, off, 64);
    minv[r] = 1.0f / z;
  }

  // ======== Pass B ========
  f32x4 oacc[4];
#pragma unroll
  for (int et = 0; et < 4; ++et) oacc[et] = (f32x4){0.f, 0.f, 0.f, 0.f};

  unsigned short* sPw = &sP[w][0];
  float* Pb = Pout + ((size_t)(b * H_ + h) * L_ + q0 + 16 * w) * L_;

  float vA[16], vB[16];
  loadV(Vb, lane, w, vA);  // chunk 0
  for (int cc = 0; cc < NCH; cc += 2) {
    storeV(&sVT[0][0], lane, w, vA);
    if (cc + 1 < NCH)
      loadV(Vb + (size_t)(cc + 1) * CHUNK * RSTRIDE, lane, w, vB);
    __syncthreads();
    computeChunk(cc, &sVT[0][0], sPw, Kb, Pb, qf0, qf1, col, kg, lane, sc_l2e,
                 sl_l2e, minv, oacc);
    storeV(&sVT[1][0], lane, w, vB);
    if (cc + 2 < NCH)
      loadV(Vb + (size_t)(cc + 2) * CHUNK * RSTRIDE, lane, w, vA);
    __syncthreads();
    computeChunk(cc + 1, &sVT[1][0], sPw, Kb, Pb, qf0, qf1, col, kg, lane,
                 sc_l2e, sl_l2e, minv, oacc);
  }

  // ---- write O ----
  float* Vo = Vout + (((size_t)b * L_ + q0 + 16 * w) * H_ + h) * E_;
#pragma unroll
  for (int et = 0; et < 4; ++et) {
#pragma unroll
    for (int r = 0; r < 4; ++r) {
      __builtin_nontemporal_store(oacc[et][r],
                                  &Vo[(4 * kg + r) * RSTRIDE + 16 * et + col]);
    }
  }
}

extern "C" void kernel_launch(void* const* d_in, const int* in_sizes, int n_in,
                              void* d_out, int out_size, void* d_ws,
                              size_t ws_size, hipStream_t stream) {
  const float* Q = (const float*)d_in[0];
  const float* K = (const float*)d_in[1];
  const float* V = (const float*)d_in[2];
  float* out = (float*)d_out;
  float* Vo = out;                              // [B,L,H,E]
  float* Po = out + (size_t)B_ * L_ * H_ * E_;  // [B,H,L,L]
  hipLaunchKernelGGL(alibi_attn, dim3((L_ / QBLK) * H_ * B_), dim3(256), 0,
                     stream, Q, K, V, Vo, Po);
}

// Round 5
// 193.330 us; speedup vs baseline: 1.2962x; 1.2962x over previous
//
#include <hip/hip_runtime.h>
#include <hip/hip_bf16.h>

// ALiBi attention, B=8 L=1024 H=8 E=64, fp32 in/out, bf16 MFMA inside.
// Outputs: V [B,L,H,E] then series [B,H,L,L] concatenated in d_out.
// Round 5: prep kernel converts K -> bf16 [bh][s][e] and V -> bf16 V^T
// [bh][e][s] in d_ws. Main kernel: two-pass fixed-max softmax, swapped
// QK^T (mfma(K,Q)), ZERO barriers, LDS = wave-private P tile only.
// K/V fragments load straight from L2-resident scratch as b128.

typedef short short8 __attribute__((ext_vector_type(8)));
typedef float f32x4 __attribute__((ext_vector_type(4)));
typedef unsigned short u16x4 __attribute__((ext_vector_type(4)));

#define B_ 8
#define L_ 1024
#define H_ 8
#define E_ 64
#define RSTRIDE (H_ * E_)  // 512 floats between seq rows of Q/K/V
#define QBLK 64            // 4 waves x 16 q-rows
#define CHUNK 64
#define NCH (L_ / CHUNK)

__device__ __forceinline__ unsigned short f2bf(float f) {
  return __builtin_bit_cast(unsigned short, __float2bfloat16(f));
}
__device__ __forceinline__ float bf2f(unsigned short u) {
  return __builtin_bit_cast(float, (unsigned int)u << 16);
}
// load 8 consecutive fp32 -> bf16x8 fragment (Q only)
__device__ __forceinline__ short8 ldfrag(const float* p) {
  float4 a = *reinterpret_cast<const float4*>(p);
  float4 b = *reinterpret_cast<const float4*>(p + 4);
  return (short8){(short)f2bf(a.x), (short)f2bf(a.y), (short)f2bf(a.z),
                  (short)f2bf(a.w), (short)f2bf(b.x), (short)f2bf(b.y),
                  (short)f2bf(b.z), (short)f2bf(b.w)};
}

// ---- prep: Kbf[bh][s][e] bf16; VT[bh][e][s] bf16. grid 16*64, 256 thr ----
__global__ __launch_bounds__(256, 4) void prep_kv(
    const float* __restrict__ Kg, const float* __restrict__ Vg,
    unsigned short* __restrict__ Kbf, unsigned short* __restrict__ VTbf) {
  __shared__ unsigned short tile[64 * 64];  // V^T subtile [e][s], swizzled

  const int t = threadIdx.x;
  const int id = blockIdx.x;
  const int bh = id & 63;  // id%8 = h -> same XCD as main kernel's consumers
  const int sc = id >> 6;  // s-chunk 0..15
  const int h = bh & 7, b = bh >> 3;
  const int s0 = sc * 64;

  const float* Kb = Kg + ((size_t)b * L_ + s0) * RSTRIDE + h * E_;
  const float* Vb = Vg + ((size_t)b * L_ + s0) * RSTRIDE + h * E_;
  unsigned short* Ko = Kbf + ((size_t)bh * L_ + s0) * E_;
  unsigned short* Vo = VTbf + (size_t)bh * E_ * L_ + s0;  // row stride L_

  {  // K convert (coalesced both sides)
    const int e = 4 * (t & 15);
#pragma unroll
    for (int i = 0; i < 4; ++i) {
      const int s = (t >> 4) + 16 * i;
      float4 v = *reinterpret_cast<const float4*>(&Kb[(size_t)s * RSTRIDE + e]);
      *reinterpret_cast<u16x4*>(&Ko[s * 64 + e]) =
          (u16x4){f2bf(v.x), f2bf(v.y), f2bf(v.z), f2bf(v.w)};
    }
  }
  {  // V transpose into LDS (lane owns column e; 256B coalesced reads)
    const int e = t & 63, w = t >> 6;
#pragma unroll
    for (int i = 0; i < 4; ++i) {
      const int s4 = 4 * w + 16 * i;
      const float* vp = &Vb[(size_t)s4 * RSTRIDE + e];
      u16x4 u = {f2bf(vp[0]), f2bf(vp[RSTRIDE]), f2bf(vp[2 * RSTRIDE]),
                 f2bf(vp[3 * RSTRIDE])};
      *reinterpret_cast<u16x4*>(
          &tile[e * 64 + (((s4 >> 3) ^ (e & 7)) << 3) + (s4 & 7)]) = u;
    }
  }
  __syncthreads();
  {  // write V^T rows (32B contiguous per thread)
    const int e = t >> 2;
    const int sb = 16 * (t & 3);
#pragma unroll
    for (int i = 0; i < 4; ++i) {
      const int sp = sb + 4 * i;
      u16x4 u = *reinterpret_cast<const u16x4*>(
          &tile[e * 64 + (((sp >> 3) ^ (e & 7)) << 3) + (sp & 7)]);
      *reinterpret_cast<u16x4*>(&Vo[(size_t)e * L_ + sp]) = u;
    }
  }
}

// ---- main: zero barriers ----
__global__ __launch_bounds__(256, 4) void alibi_attn(
    const float* __restrict__ Qg, const unsigned short* __restrict__ Kbf,
    const unsigned short* __restrict__ VTbf, float* __restrict__ Vout,
    float* __restrict__ Pout) {
  __shared__ unsigned short sP[4][16 * 64];  // wave-private P [q][key], swz

  const int t = threadIdx.x;
  const int lane = t & 63;
  const int w = t >> 6;
  const int col = lane & 15;
  const int kg = lane >> 4;

  const int id = blockIdx.x;  // id%8 = h -> XCD-pinned K/V/VT in L2
  const int qb = id >> 6;
  const int bh = id & 63;
  const int h = bh & 7;
  const int b = bh >> 3;
  const int q0 = qb * QBLK;

  const float sc_l2e = 0.125f * 1.44269504f;
  const float sl_l2e = exp2f(-(float)(h + 1) * 0.125f) * 1.44269504f;

  const unsigned short* Kb = Kbf + (size_t)bh * (L_ * E_);
  const unsigned short* VTb = VTbf + (size_t)bh * (E_ * L_);

  // Q B-fragments: q-row = col, k = 8*kg + j (+32 for second slice)
  short8 qf0, qf1;
  {
    const float* qp =
        Qg + ((size_t)b * L_ + q0 + 16 * w + col) * RSTRIDE + h * E_ + 8 * kg;
    qf0 = ldfrag(qp);
    qf1 = ldfrag(qp + 32);
  }

  // ===== Pass A: z[q=col] = sum_keys exp2(u - 32)  (swapped: mfma(K,Q)) =====
  float z = 0.f;
#pragma unroll 8
  for (int kt = 0; kt < L_ / 16; ++kt) {
    const unsigned short* kp = Kb + (16 * kt + col) * E_ + 8 * kg;
    short8 k0 = *reinterpret_cast<const short8*>(kp);
    short8 k1 = *reinterpret_cast<const short8*>(kp + 32);
    f32x4 acc = {0.f, 0.f, 0.f, 0.f};
    acc = __builtin_amdgcn_mfma_f32_16x16x32_bf16(k0, qf0, acc, 0, 0, 0);
    acc = __builtin_amdgcn_mfma_f32_16x16x32_bf16(k1, qf1, acc, 0, 0, 0);
    const float kb = (float)(16 * kt + 4 * kg);
#pragma unroll
    for (int r = 0; r < 4; ++r)
      z += exp2f(acc[r] * sc_l2e + sl_l2e * (kb + (float)r - 1023.0f) - 32.0f);
  }
  z += __shfl_xor(z, 16, 64);
  z += __shfl_xor(z, 32, 64);
  const float minv = 1.0f / z;

  // ===== Pass B =====
  f32x4 oacc[4];
#pragma unroll
  for (int et = 0; et < 4; ++et) oacc[et] = (f32x4){0.f, 0.f, 0.f, 0.f};

  unsigned short* sPw = &sP[w][0];
  float* Pb = Pout + ((size_t)(b * H_ + h) * L_ + q0 + 16 * w) * L_;

  for (int c = 0; c < NCH; ++c) {
    // QK^T (swapped) -> P packed pairs -> wave-private LDS (no barriers)
#pragma unroll
    for (int kt = 0; kt < 4; ++kt) {
      const unsigned short* kp =
          Kb + (c * CHUNK + 16 * kt + col) * E_ + 8 * kg;
      short8 k0 = *reinterpret_cast<const short8*>(kp);
      short8 k1 = *reinterpret_cast<const short8*>(kp + 32);
      f32x4 acc = {0.f, 0.f, 0.f, 0.f};
      acc = __builtin_amdgcn_mfma_f32_16x16x32_bf16(k0, qf0, acc, 0, 0, 0);
      acc = __builtin_amdgcn_mfma_f32_16x16x32_bf16(k1, qf1, acc, 0, 0, 0);
      const float kb = (float)(c * CHUNK + 16 * kt + 4 * kg);
      unsigned int pw0, pw1;
      {
        float p0 = exp2f(acc[0] * sc_l2e + sl_l2e * (kb - 1023.f) - 32.f) * minv;
        float p1 = exp2f(acc[1] * sc_l2e + sl_l2e * (kb - 1022.f) - 32.f) * minv;
        float p2 = exp2f(acc[2] * sc_l2e + sl_l2e * (kb - 1021.f) - 32.f) * minv;
        float p3 = exp2f(acc[3] * sc_l2e + sl_l2e * (kb - 1020.f) - 32.f) * minv;
        pw0 = (unsigned int)f2bf(p0) | ((unsigned int)f2bf(p1) << 16);
        pw1 = (unsigned int)f2bf(p2) | ((unsigned int)f2bf(p3) << 16);
      }
      const int g = 2 * kt + (kg >> 1);
      unsigned long long wv =
          (unsigned long long)pw0 | ((unsigned long long)pw1 << 32);
      *reinterpret_cast<unsigned long long*>(
          &sPw[col * 64 + ((g ^ (col & 7)) << 3) + 4 * (kg & 1)]) = wv;
    }

    // PV: A = P (q=col rows from sP), B = V^T direct from global/L2
#pragma unroll
    for (int ks = 0; ks < 2; ++ks) {
      short8 af = *reinterpret_cast<const short8*>(
          &sPw[col * 64 + (((4 * ks + kg) ^ (col & 7)) << 3)]);
#pragma unroll
      for (int et = 0; et < 4; ++et) {
        short8 vf = *reinterpret_cast<const short8*>(
            &VTb[(size_t)(16 * et + col) * L_ + c * CHUNK + 32 * ks + 8 * kg]);
        oacc[et] =
            __builtin_amdgcn_mfma_f32_16x16x32_bf16(af, vf, oacc[et], 0, 0, 0);
      }
    }

    // coalesced P writeback (LDS -> fp32 rows, nontemporal)
#pragma unroll
    for (int i = 0; i < 4; ++i) {
      const int f = i * 64 + lane;
      const int row = f >> 4;
      const int c0 = 4 * (f & 15);
      u16x4 u = *reinterpret_cast<const u16x4*>(
          &sPw[row * 64 + (((c0 >> 3) ^ (row & 7)) << 3) + (c0 & 7)]);
      f32x4 o = {bf2f(u[0]), bf2f(u[1]), bf2f(u[2]), bf2f(u[3])};
      __builtin_nontemporal_store(
          o, reinterpret_cast<f32x4*>(&Pb[(size_t)row * L_ + c * CHUNK + c0]));
    }
  }

  // ---- write O: q = q0+16w+4kg+r, e = 16et+col ----
  float* Vo = Vout + (((size_t)b * L_ + q0 + 16 * w) * H_ + h) * E_;
#pragma unroll
  for (int et = 0; et < 4; ++et) {
#pragma unroll
    for (int r = 0; r < 4; ++r) {
      __builtin_nontemporal_store(oacc[et][r],
                                  &Vo[(4 * kg + r) * RSTRIDE + 16 * et + col]);
    }
  }
}

extern "C" void kernel_launch(void* const* d_in, const int* in_sizes, int n_in,
                              void* d_out, int out_size, void* d_ws,
                              size_t ws_size, hipStream_t stream) {
  const float* Q = (const float*)d_in[0];
  const float* K = (const float*)d_in[1];
  const float* V = (const float*)d_in[2];
  float* out = (float*)d_out;
  float* Vo = out;                              // [B,L,H,E]
  float* Po = out + (size_t)B_ * L_ * H_ * E_;  // [B,H,L,L]
  unsigned short* Kbf = (unsigned short*)d_ws;  // 8 MB
  unsigned short* VTbf = Kbf + (size_t)B_ * H_ * L_ * E_;  // 8 MB
  hipLaunchKernelGGL(prep_kv, dim3(16 * B_ * H_), dim3(256), 0, stream, K, V,
                     Kbf, VTbf);
  hipLaunchKernelGGL(alibi_attn, dim3((L_ / QBLK) * H_ * B_), dim3(256), 0,
                     stream, Q, Kbf, VTbf, Vo, Po);
}